// Round 7
// baseline (546.914 us; speedup 1.0000x reference)
//
#include <hip/hip_runtime.h>
#include <hip/hip_bf16.h>

#define N_PTS 1500000
#define NT_TILES (N_PTS / 16)   // 93750, exact
#define CBCH 96
#define CTCH 128
#define COCH 96
#define NB 8
#define BN_EPS 1e-5f
#define GRID1 1024
#define NSTREAM (GRID1 * 4)     // 4 tile-streams per block (each stream = 2 waves, one per channel-half)
#define STPAD 100               // sT row stride (floats)

// ws float offsets
#define GSUM_OFF 0
#define GSQ_OFF 96

typedef __attribute__((ext_vector_type(8))) short bf16x8;
typedef __attribute__((ext_vector_type(4))) float f32x4;

__device__ __forceinline__ short f2bf(float f) {
    __hip_bfloat16 h = __float2bfloat16(f);
    short s;
    __builtin_memcpy(&s, &h, sizeof(s));
    return s;
}

// k0z: zero stats accumulators.
__global__ void k0z(float* __restrict__ ws) {
    if (threadIdx.x < 192) ws[threadIdx.x] = 0.f;
}

// ---------------------------------------------------------------------------
// MFMA 16x16x32 bf16, swapped form: A = W^T frag (row=channel), B = points
// (col=point). Lane (grp=l>>4, lr=l&15) owns channels (half*3+ct)*16+grp*4+[0..3]
// of point base+lr. Each wave handles 3 of the 6 ct-tiles (half = wv>>2).

__device__ __forceinline__ void stage_W(const float* __restrict__ W, short* sW) {
    for (int i = threadIdx.x; i < CBCH * COCH; i += blockDim.x) {
        int k = i / COCH, c = i % COCH;               // W[k][c], coalesced read
        int ct = c >> 4, lr = c & 15;
        int kt = k >> 5, grp = (k >> 3) & 3, j = k & 7;
        sW[(((ct * 3 + kt) * 64) + (grp * 16 + lr)) * 8 + j] = f2bf(W[i]);
    }
}

__device__ __forceinline__ void load_bfrag_half(const short* sW, int lane, int half,
                                                bf16x8 bf[3][3]) {
    #pragma unroll
    for (int ct = 0; ct < 3; ++ct)
        #pragma unroll
        for (int kt = 0; kt < 3; ++kt)
            bf[ct][kt] = *reinterpret_cast<const bf16x8*>(
                sW + (((half * 3 + ct) * 3 + kt) * 64 + lane) * 8);
}

// Issue the 6 16B raw loads of this lane's point row (k-slices grp*8..grp*8+7 of each kt).
__device__ __forceinline__ void issue_raw(const float* __restrict__ bb, int base,
                                          int grp, int lr, f32x4 r[6]) {
    const f32x4* q = reinterpret_cast<const f32x4*>(bb + (size_t)(base + lr) * CBCH + grp * 8);
    #pragma unroll
    for (int kt = 0; kt < 3; ++kt) {
        r[2 * kt]     = q[kt * 8];
        r[2 * kt + 1] = q[kt * 8 + 1];
    }
}

__device__ __forceinline__ void cvt_pf(const f32x4 r[6], bf16x8 pf[3]) {
    #pragma unroll
    for (int kt = 0; kt < 3; ++kt)
        #pragma unroll
        for (int j = 0; j < 4; ++j) {
            pf[kt][j]     = f2bf(r[2 * kt][j]);
            pf[kt][4 + j] = f2bf(r[2 * kt + 1][j]);
        }
}

// K1: stats pass (software-pipelined: issue t+1 loads, compute t).
__global__ __launch_bounds__(512, 4) void k1_stats(const float* __restrict__ bb,
                                                   const int* __restrict__ bidx,
                                                   const float* __restrict__ text,
                                                   const float* __restrict__ W,
                                                   float* __restrict__ ws) {
    __shared__ __align__(16) short sW[6 * 3 * 64 * 8];   // 18 KB
    __shared__ __align__(16) float sT[NB * STPAD];
    __shared__ float sredS[4][COCH];
    __shared__ float sredQ[4][COCH];

    stage_W(W, sW);
    for (int i = threadIdx.x; i < NB * COCH; i += blockDim.x) {
        int b = i / COCH, c = i % COCH;
        float acc = 0.f;
        #pragma unroll 8
        for (int k = 0; k < CTCH; ++k)
            acc += text[b * CTCH + k] * W[(CBCH + k) * COCH + c];
        sT[b * STPAD + c] = acc;
    }
    __syncthreads();

    const int lane = threadIdx.x & 63;
    const int wv = threadIdx.x >> 6;          // 0..7
    const int half = wv >> 2;
    const int stream = wv & 3;
    const int grp = lane >> 4, lr = lane & 15;

    bf16x8 bf[3][3];
    load_bfrag_half(sW, lane, half, bf);

    f32x4 sum[3], sq[3];
    #pragma unroll
    for (int ct = 0; ct < 3; ++ct) { sum[ct] = (f32x4)0.f; sq[ct] = (f32x4)0.f; }

    int t = blockIdx.x * 4 + stream;
    int b_cur = 0;
    f32x4 r[6];
    if (t < NT_TILES) { b_cur = bidx[t * 16 + lr]; issue_raw(bb, t * 16, grp, lr, r); }

    while (t < NT_TILES) {
        int tn = t + NSTREAM;
        int b_nxt = 0;
        f32x4 rn[6];
        if (tn < NT_TILES) {                       // wave-uniform branch
            b_nxt = bidx[tn * 16 + lr];
            issue_raw(bb, tn * 16, grp, lr, rn);   // in flight during compute below
        }

        f32x4 acc[3];
        #pragma unroll
        for (int ct = 0; ct < 3; ++ct)
            acc[ct] = *reinterpret_cast<const f32x4*>(&sT[b_cur * STPAD + (half * 3 + ct) * 16 + grp * 4]);
        bf16x8 pf[3];
        cvt_pf(r, pf);
        #pragma unroll
        for (int ct = 0; ct < 3; ++ct)
            #pragma unroll
            for (int kt = 0; kt < 3; ++kt)
                acc[ct] = __builtin_amdgcn_mfma_f32_16x16x32_bf16(bf[ct][kt], pf[kt], acc[ct], 0, 0, 0);
        #pragma unroll
        for (int ct = 0; ct < 3; ++ct) {
            sum[ct] += acc[ct];
            sq[ct] += acc[ct] * acc[ct];
        }

        b_cur = b_nxt;
        #pragma unroll
        for (int i = 0; i < 6; ++i) r[i] = rn[i];
        t = tn;
    }

    #pragma unroll
    for (int ct = 0; ct < 3; ++ct)
        #pragma unroll
        for (int rr = 0; rr < 4; ++rr) {
            float s = sum[ct][rr], q = sq[ct][rr];
            s += __shfl_xor(s, 1);  q += __shfl_xor(q, 1);
            s += __shfl_xor(s, 2);  q += __shfl_xor(q, 2);
            s += __shfl_xor(s, 4);  q += __shfl_xor(q, 4);
            s += __shfl_xor(s, 8);  q += __shfl_xor(q, 8);
            if (lr == 0) {
                sredS[stream][half * 48 + ct * 16 + grp * 4 + rr] = s;
                sredQ[stream][half * 48 + ct * 16 + grp * 4 + rr] = q;
            }
        }
    __syncthreads();
    if (threadIdx.x < COCH) {
        int c = threadIdx.x;
        atomicAdd(&ws[GSUM_OFF + c], sredS[0][c] + sredS[1][c] + sredS[2][c] + sredS[3][c]);
        atomicAdd(&ws[GSQ_OFF + c],  sredQ[0][c] + sredQ[1][c] + sredQ[2][c] + sredQ[3][c]);
    }
}

// K3: output pass — pipelined like k1; scale/bias read from LDS per tile
// (saves 24 VGPRs); reverse tile order for L3 reuse; NT stores.
__global__ __launch_bounds__(512, 4) void k3_out(const float* __restrict__ bb,
                                                 const int* __restrict__ bidx,
                                                 const float* __restrict__ text,
                                                 const float* __restrict__ W,
                                                 const float* __restrict__ gamma,
                                                 const float* __restrict__ beta,
                                                 const float* __restrict__ ws,
                                                 float* __restrict__ out) {
    __shared__ __align__(16) short sW[6 * 3 * 64 * 8];
    __shared__ __align__(16) float sT[NB * STPAD];
    __shared__ __align__(16) float sScale[COCH];
    __shared__ __align__(16) float sBias[COCH];

    stage_W(W, sW);
    for (int i = threadIdx.x; i < NB * COCH; i += blockDim.x) {
        int b = i / COCH, c = i % COCH;
        float acc = 0.f;
        #pragma unroll 8
        for (int k = 0; k < CTCH; ++k)
            acc += text[b * CTCH + k] * W[(CBCH + k) * COCH + c];
        sT[b * STPAD + c] = acc;
    }
    if (threadIdx.x < COCH) {
        int c = threadIdx.x;
        float mean = ws[GSUM_OFF + c] * (1.f / (float)N_PTS);
        float var  = ws[GSQ_OFF + c] * (1.f / (float)N_PTS) - mean * mean;
        float scl  = gamma[c] * rsqrtf(var + BN_EPS);
        sScale[c] = scl;
        sBias[c]  = beta[c] - mean * scl;
    }
    __syncthreads();

    const int lane = threadIdx.x & 63;
    const int wv = threadIdx.x >> 6;
    const int half = wv >> 2;
    const int stream = wv & 3;
    const int grp = lane >> 4, lr = lane & 15;

    bf16x8 bf[3][3];
    load_bfrag_half(sW, lane, half, bf);

    int t = NT_TILES - 1 - (blockIdx.x * 4 + stream);
    int b_cur = 0;
    f32x4 r[6];
    if (t >= 0) { b_cur = bidx[t * 16 + lr]; issue_raw(bb, t * 16, grp, lr, r); }

    while (t >= 0) {
        int tn = t - NSTREAM;
        int b_nxt = 0;
        f32x4 rn[6];
        if (tn >= 0) {
            b_nxt = bidx[tn * 16 + lr];
            issue_raw(bb, tn * 16, grp, lr, rn);
        }

        int base = t * 16;
        f32x4 acc[3];
        #pragma unroll
        for (int ct = 0; ct < 3; ++ct)
            acc[ct] = *reinterpret_cast<const f32x4*>(&sT[b_cur * STPAD + (half * 3 + ct) * 16 + grp * 4]);
        bf16x8 pf[3];
        cvt_pf(r, pf);
        #pragma unroll
        for (int ct = 0; ct < 3; ++ct)
            #pragma unroll
            for (int kt = 0; kt < 3; ++kt)
                acc[ct] = __builtin_amdgcn_mfma_f32_16x16x32_bf16(bf[ct][kt], pf[kt], acc[ct], 0, 0, 0);

        #pragma unroll
        for (int ct = 0; ct < 3; ++ct) {
            f32x4 sc = *reinterpret_cast<const f32x4*>(&sScale[(half * 3 + ct) * 16 + grp * 4]);
            f32x4 bs = *reinterpret_cast<const f32x4*>(&sBias[(half * 3 + ct) * 16 + grp * 4]);
            f32x4 y;
            #pragma unroll
            for (int rr = 0; rr < 4; ++rr)
                y[rr] = fmaxf(acc[ct][rr] * sc[rr] + bs[rr], 0.f);
            __builtin_nontemporal_store(y,
                reinterpret_cast<f32x4*>(out + (size_t)(base + lr) * COCH + (half * 3 + ct) * 16 + grp * 4));
        }

        b_cur = b_nxt;
        #pragma unroll
        for (int i = 0; i < 6; ++i) r[i] = rn[i];
        t = tn;
    }
}

extern "C" void kernel_launch(void* const* d_in, const int* in_sizes, int n_in,
                              void* d_out, int out_size, void* d_ws, size_t ws_size,
                              hipStream_t stream) {
    const float* bb    = (const float*)d_in[0];
    const int*   bidx  = (const int*)d_in[1];
    const float* text  = (const float*)d_in[2];
    const float* W     = (const float*)d_in[3];
    const float* gamma = (const float*)d_in[4];
    const float* beta  = (const float*)d_in[5];
    float* out = (float*)d_out;
    float* ws  = (float*)d_ws;

    hipLaunchKernelGGL(k0z, dim3(1), dim3(256), 0, stream, ws);
    hipLaunchKernelGGL(k1_stats, dim3(GRID1), dim3(512), 0, stream, bb, bidx, text, W, ws);
    hipLaunchKernelGGL(k3_out, dim3(GRID1), dim3(512), 0, stream, bb, bidx, text, W, gamma, beta, ws, out);
}

// Round 8
// 505.109 us; speedup vs baseline: 1.0828x; 1.0828x over previous
//
#include <hip/hip_runtime.h>
#include <hip/hip_bf16.h>

#define N_PTS 1500000
#define NT_TILES (N_PTS / 16)   // 93750, exact
#define CBCH 96
#define CTCH 128
#define COCH 96
#define NB 8
#define BN_EPS 1e-5f
#define GRID1 2048
#define NWAVE (GRID1 * 4)
#define STPAD 100               // sT row stride (floats)

// ws float offsets
#define GSUM_OFF 0
#define GSQ_OFF 96

typedef __attribute__((ext_vector_type(8))) short bf16x8;
typedef __attribute__((ext_vector_type(4))) float f32x4;

__device__ __forceinline__ short f2bf(float f) {
    __hip_bfloat16 h = __float2bfloat16(f);
    short s;
    __builtin_memcpy(&s, &h, sizeof(s));
    return s;
}

// k0z: zero stats accumulators.
__global__ void k0z(float* __restrict__ ws) {
    if (threadIdx.x < 192) ws[threadIdx.x] = 0.f;
}

// ---------------------------------------------------------------------------
// MFMA 16x16x32 bf16, swapped form: A = W^T frag (row=channel), B = points
// (col=point). Lane (grp=l>>4, lr=l&15) owns channels ct*16+grp*4+[0..3] of
// point base+lr.
//
// K-PERMUTATION for dense loads: fragment position (grp, j) holds
//   k_eff = kt*32 + (j<4 ? grp*4+j : 16+grp*4+(j-4))
// Both operands use the same k_eff mapping, so the contraction is unchanged.
// Point-side loads become float4 at row*384B + kt*128B + grp*16B (+64B):
// each instruction's 64 lanes = 16 complete 64B lines, 100% coverage.

__device__ __forceinline__ void stage_W(const float* __restrict__ W, short* sW) {
    for (int i = threadIdx.x; i < CBCH * COCH; i += blockDim.x) {
        int k = i / COCH, c = i % COCH;               // W[k][c], coalesced read
        int ct = c >> 4, lr = c & 15;
        int kt = k >> 5, r5 = k & 31;
        int grp = (r5 & 15) >> 2;
        int j = (r5 & 3) + ((r5 >> 4) << 2);          // r5<16 -> j=0..3, r5>=16 -> j=4..7
        sW[(((ct * 3 + kt) * 64) + (grp * 16 + lr)) * 8 + j] = f2bf(W[i]);
    }
}

__device__ __forceinline__ void load_bfrag_lds(const short* sW, int lane, bf16x8 bf[6][3]) {
    #pragma unroll
    for (int ct = 0; ct < 6; ++ct)
        #pragma unroll
        for (int kt = 0; kt < 3; ++kt)
            bf[ct][kt] = *reinterpret_cast<const bf16x8*>(sW + ((ct * 3 + kt) * 64 + lane) * 8);
}

// One 16-point tile: gather T[bidx] into acc, dense-load + convert, 18 MFMAs.
__device__ __forceinline__ void tile_acc(const float* __restrict__ bb,
                                         const int* __restrict__ bidx,
                                         const float* __restrict__ sT,
                                         const bf16x8 bf[6][3],
                                         int base, int grp, int lr,
                                         f32x4 acc[6]) {
    int b = bidx[base + lr];
    #pragma unroll
    for (int ct = 0; ct < 6; ++ct)
        acc[ct] = *reinterpret_cast<const f32x4*>(&sT[b * STPAD + ct * 16 + grp * 4]);

    // dense loads: float4 at row*96 + kt*32 + grp*4 and +16 (floats)
    const f32x4* q = reinterpret_cast<const f32x4*>(bb + (size_t)(base + lr) * CBCH + grp * 4);
    bf16x8 pf[3];
    #pragma unroll
    for (int kt = 0; kt < 3; ++kt) {
        f32x4 x0 = q[kt * 8];        // k_eff = kt*32 + grp*4 + {0..3}
        f32x4 x1 = q[kt * 8 + 4];    // k_eff = kt*32 + 16 + grp*4 + {0..3}
        #pragma unroll
        for (int j = 0; j < 4; ++j) {
            pf[kt][j]     = f2bf(x0[j]);
            pf[kt][4 + j] = f2bf(x1[j]);
        }
    }
    #pragma unroll
    for (int ct = 0; ct < 6; ++ct)
        #pragma unroll
        for (int kt = 0; kt < 3; ++kt)
            acc[ct] = __builtin_amdgcn_mfma_f32_16x16x32_bf16(bf[ct][kt], pf[kt], acc[ct], 0, 0, 0);
}

// K1: stats pass — compute x, accumulate per-channel sum & sumsq, discard x.
__global__ __launch_bounds__(256, 2) void k1_stats(const float* __restrict__ bb,
                                                   const int* __restrict__ bidx,
                                                   const float* __restrict__ text,
                                                   const float* __restrict__ W,
                                                   float* __restrict__ ws) {
    __shared__ __align__(16) short sW[6 * 3 * 64 * 8];   // 18 KB
    __shared__ __align__(16) float sT[NB * STPAD];
    __shared__ float sredS[4][COCH];
    __shared__ float sredQ[4][COCH];

    stage_W(W, sW);
    for (int i = threadIdx.x; i < NB * COCH; i += blockDim.x) {
        int b = i / COCH, c = i % COCH;
        float acc = 0.f;
        #pragma unroll 8
        for (int k = 0; k < CTCH; ++k)
            acc += text[b * CTCH + k] * W[(CBCH + k) * COCH + c];
        sT[b * STPAD + c] = acc;
    }
    __syncthreads();

    const int lane = threadIdx.x & 63;
    const int wv = threadIdx.x >> 6;
    const int grp = lane >> 4, lr = lane & 15;

    bf16x8 bf[6][3];
    load_bfrag_lds(sW, lane, bf);

    f32x4 sum[6], sq[6];
    #pragma unroll
    for (int ct = 0; ct < 6; ++ct) { sum[ct] = (f32x4)0.f; sq[ct] = (f32x4)0.f; }

    const int gw = blockIdx.x * 4 + wv;
    for (int t = gw; t < NT_TILES; t += NWAVE) {
        int base = t * 16;
        f32x4 acc[6];
        tile_acc(bb, bidx, sT, bf, base, grp, lr, acc);
        #pragma unroll
        for (int ct = 0; ct < 6; ++ct) {
            sum[ct] += acc[ct];
            sq[ct] += acc[ct] * acc[ct];
        }
    }

    // reduce over lr (16 lanes of same grp hold same channels, different points)
    #pragma unroll
    for (int ct = 0; ct < 6; ++ct)
        #pragma unroll
        for (int r = 0; r < 4; ++r) {
            float s = sum[ct][r], q = sq[ct][r];
            s += __shfl_xor(s, 1);  q += __shfl_xor(q, 1);
            s += __shfl_xor(s, 2);  q += __shfl_xor(q, 2);
            s += __shfl_xor(s, 4);  q += __shfl_xor(q, 4);
            s += __shfl_xor(s, 8);  q += __shfl_xor(q, 8);
            if (lr == 0) {
                sredS[wv][ct * 16 + grp * 4 + r] = s;
                sredQ[wv][ct * 16 + grp * 4 + r] = q;
            }
        }
    __syncthreads();
    if (threadIdx.x < COCH) {
        int c = threadIdx.x;
        atomicAdd(&ws[GSUM_OFF + c], sredS[0][c] + sredS[1][c] + sredS[2][c] + sredS[3][c]);
        atomicAdd(&ws[GSQ_OFF + c],  sredQ[0][c] + sredQ[1][c] + sredQ[2][c] + sredQ[3][c]);
    }
}

// K3: output pass — finalize scale/bias in prologue, recompute x, normalize +
// ReLU, NT store. Reverse tile order hits pass-1's L3-resident backbone tail.
__global__ __launch_bounds__(256, 2) void k3_out(const float* __restrict__ bb,
                                                 const int* __restrict__ bidx,
                                                 const float* __restrict__ text,
                                                 const float* __restrict__ W,
                                                 const float* __restrict__ gamma,
                                                 const float* __restrict__ beta,
                                                 const float* __restrict__ ws,
                                                 float* __restrict__ out) {
    __shared__ __align__(16) short sW[6 * 3 * 64 * 8];
    __shared__ __align__(16) float sT[NB * STPAD];
    __shared__ __align__(16) float sScale[COCH];
    __shared__ __align__(16) float sBias[COCH];

    stage_W(W, sW);
    for (int i = threadIdx.x; i < NB * COCH; i += blockDim.x) {
        int b = i / COCH, c = i % COCH;
        float acc = 0.f;
        #pragma unroll 8
        for (int k = 0; k < CTCH; ++k)
            acc += text[b * CTCH + k] * W[(CBCH + k) * COCH + c];
        sT[b * STPAD + c] = acc;
    }
    if (threadIdx.x < COCH) {
        int c = threadIdx.x;
        float mean = ws[GSUM_OFF + c] * (1.f / (float)N_PTS);
        float var  = ws[GSQ_OFF + c] * (1.f / (float)N_PTS) - mean * mean;
        float scl  = gamma[c] * rsqrtf(var + BN_EPS);
        sScale[c] = scl;
        sBias[c]  = beta[c] - mean * scl;
    }
    __syncthreads();

    const int lane = threadIdx.x & 63;
    const int wv = threadIdx.x >> 6;
    const int grp = lane >> 4, lr = lane & 15;

    bf16x8 bf[6][3];
    load_bfrag_lds(sW, lane, bf);

    f32x4 sc[6], bs[6];
    #pragma unroll
    for (int ct = 0; ct < 6; ++ct) {
        sc[ct] = *reinterpret_cast<const f32x4*>(&sScale[ct * 16 + grp * 4]);
        bs[ct] = *reinterpret_cast<const f32x4*>(&sBias[ct * 16 + grp * 4]);
    }

    const int gw = blockIdx.x * 4 + wv;
    for (int t = NT_TILES - 1 - gw; t >= 0; t -= NWAVE) {
        int base = t * 16;
        f32x4 acc[6];
        tile_acc(bb, bidx, sT, bf, base, grp, lr, acc);
        #pragma unroll
        for (int ct = 0; ct < 6; ++ct) {
            f32x4 y;
            #pragma unroll
            for (int r = 0; r < 4; ++r)
                y[r] = fmaxf(acc[ct][r] * sc[ct][r] + bs[ct][r], 0.f);
            __builtin_nontemporal_store(y,
                reinterpret_cast<f32x4*>(out + (size_t)(base + lr) * COCH + ct * 16 + grp * 4));
        }
    }
}

extern "C" void kernel_launch(void* const* d_in, const int* in_sizes, int n_in,
                              void* d_out, int out_size, void* d_ws, size_t ws_size,
                              hipStream_t stream) {
    const float* bb    = (const float*)d_in[0];
    const int*   bidx  = (const int*)d_in[1];
    const float* text  = (const float*)d_in[2];
    const float* W     = (const float*)d_in[3];
    const float* gamma = (const float*)d_in[4];
    const float* beta  = (const float*)d_in[5];
    float* out = (float*)d_out;
    float* ws  = (float*)d_ws;

    hipLaunchKernelGGL(k0z, dim3(1), dim3(256), 0, stream, ws);
    hipLaunchKernelGGL(k1_stats, dim3(GRID1), dim3(256), 0, stream, bb, bidx, text, W, ws);
    hipLaunchKernelGGL(k3_out, dim3(GRID1), dim3(256), 0, stream, bb, bidx, text, W, gamma, beta, ws, out);
}

// Round 9
// 466.230 us; speedup vs baseline: 1.1731x; 1.0834x over previous
//
#include <hip/hip_runtime.h>
#include <hip/hip_bf16.h>

#define N_PTS 1500000
#define NT_TILES (N_PTS / 16)   // 93750, exact
#define CBCH 96
#define CTCH 128
#define COCH 96
#define NB 8
#define BN_EPS 1e-5f
#define GRID1 512               // R3's proven config for the GEMM pass
#define NWAVE (GRID1 * 4)
#define STPAD 100               // sT row stride (floats)

// ws float offsets
#define GSUM_OFF 0
#define GSQ_OFF 96
#define T_OFF 384               // 8*96 floats (text @ W_bottom)
#define STASH_OFF_F 1024        // bf16 stash starts here (4KB aligned)
#define STASH_BYTES ((size_t)N_PTS * COCH * 2)
#define WS_NEEDED (STASH_OFF_F * 4 + STASH_BYTES)

typedef __attribute__((ext_vector_type(8))) short bf16x8;
typedef __attribute__((ext_vector_type(8))) short short8;
typedef __attribute__((ext_vector_type(4))) float f32x4;

__device__ __forceinline__ short f2bf(float f) {
    __hip_bfloat16 h = __float2bfloat16(f);
    short s;
    __builtin_memcpy(&s, &h, sizeof(s));
    return s;
}

// K0: blocks 0..7 compute T[b][:] = text[b,:] @ W[96:224,:]; block 8 zeroes stats.
__global__ void k0_init(const float* __restrict__ text, const float* __restrict__ W,
                        float* __restrict__ ws) {
    if (blockIdx.x == NB) {
        for (int i = threadIdx.x; i < 192; i += blockDim.x) ws[i] = 0.f;
        return;
    }
    int b = blockIdx.x;
    int c = threadIdx.x;
    if (c < COCH) {
        float acc = 0.f;
        #pragma unroll 8
        for (int k = 0; k < CTCH; ++k)
            acc += text[b * CTCH + k] * W[(CBCH + k) * COCH + c];
        ws[T_OFF + b * COCH + c] = acc;
    }
}

// ---------------------------------------------------------------------------
// MFMA 16x16x32 bf16, swapped form: A = W^T frag (row=channel), B = points
// (col=point). Lane (grp=l>>4, lr=l&15) owns channels ct*16+grp*4+[0..3] of
// point base+lr.  (R3-verbatim fragment layout.)

__device__ __forceinline__ void stage_W(const float* __restrict__ W, short* sW) {
    for (int i = threadIdx.x; i < CBCH * COCH; i += blockDim.x) {
        int k = i / COCH, c = i % COCH;               // W[k][c], coalesced read
        int ct = c >> 4, lr = c & 15;
        int kt = k >> 5, grp = (k >> 3) & 3, j = k & 7;
        sW[(((ct * 3 + kt) * 64) + (grp * 16 + lr)) * 8 + j] = f2bf(W[i]);
    }
}

__device__ __forceinline__ void load_bfrag_lds(const short* sW, int lane, bf16x8 bf[6][3]) {
    #pragma unroll
    for (int ct = 0; ct < 6; ++ct)
        #pragma unroll
        for (int kt = 0; kt < 3; ++kt)
            bf[ct][kt] = *reinterpret_cast<const bf16x8*>(sW + ((ct * 3 + kt) * 64 + lane) * 8);
}

template <bool NTLOAD>
__device__ __forceinline__ void tile_acc(const float* __restrict__ bb,
                                         const int* __restrict__ bidx,
                                         const float* __restrict__ sT,
                                         const bf16x8 bf[6][3],
                                         int base, int grp, int lr,
                                         f32x4 acc[6]) {
    int b = bidx[base + lr];
    #pragma unroll
    for (int ct = 0; ct < 6; ++ct)
        acc[ct] = *reinterpret_cast<const f32x4*>(&sT[b * STPAD + ct * 16 + grp * 4]);

    bf16x8 pf[3];
    #pragma unroll
    for (int kt = 0; kt < 3; ++kt) {
        const f32x4* p = reinterpret_cast<const f32x4*>(bb + (size_t)(base + lr) * CBCH + kt * 32 + grp * 8);
        f32x4 x0, x1;
        if (NTLOAD) { x0 = __builtin_nontemporal_load(p); x1 = __builtin_nontemporal_load(p + 1); }
        else        { x0 = p[0]; x1 = p[1]; }
        #pragma unroll
        for (int j = 0; j < 4; ++j) {
            pf[kt][j]     = f2bf(x0[j]);
            pf[kt][4 + j] = f2bf(x1[j]);
        }
    }
    #pragma unroll
    for (int ct = 0; ct < 6; ++ct)
        #pragma unroll
        for (int kt = 0; kt < 3; ++kt)
            acc[ct] = __builtin_amdgcn_mfma_f32_16x16x32_bf16(bf[ct][kt], pf[kt], acc[ct], 0, 0, 0);
}

// K1: stats pass + optional bf16 stash of x. R3 structure verbatim otherwise.
__global__ __launch_bounds__(256, 2) void k1_stats(const float* __restrict__ bb,
                                                   const int* __restrict__ bidx,
                                                   const float* __restrict__ W,
                                                   float* __restrict__ ws,
                                                   int do_stash) {
    __shared__ __align__(16) short sW[6 * 3 * 64 * 8];   // 18 KB
    __shared__ __align__(16) float sT[NB * STPAD];
    __shared__ float sredS[4][COCH];
    __shared__ float sredQ[4][COCH];

    stage_W(W, sW);
    for (int i = threadIdx.x; i < NB * COCH; i += blockDim.x)
        sT[(i / COCH) * STPAD + (i % COCH)] = ws[T_OFF + i];
    __syncthreads();

    const int lane = threadIdx.x & 63;
    const int wv = threadIdx.x >> 6;
    const int grp = lane >> 4, lr = lane & 15;

    bf16x8 bf[6][3];
    load_bfrag_lds(sW, lane, bf);

    short* stash = (short*)(ws + STASH_OFF_F);

    f32x4 sum[6], sq[6];
    #pragma unroll
    for (int ct = 0; ct < 6; ++ct) { sum[ct] = (f32x4)0.f; sq[ct] = (f32x4)0.f; }

    const int gw = blockIdx.x * 4 + wv;
    for (int t = gw; t < NT_TILES; t += NWAVE) {
        int base = t * 16;
        f32x4 acc[6];
        tile_acc<true>(bb, bidx, sT, bf, base, grp, lr, acc);
        #pragma unroll
        for (int ct = 0; ct < 6; ++ct) {
            sum[ct] += acc[ct];
            sq[ct] += acc[ct] * acc[ct];
        }
        if (do_stash) {   // wave-uniform
            #pragma unroll
            for (int ct = 0; ct < 6; ++ct) {
                unsigned lo = (unsigned short)f2bf(acc[ct][0]) | ((unsigned)(unsigned short)f2bf(acc[ct][1]) << 16);
                unsigned hi = (unsigned short)f2bf(acc[ct][2]) | ((unsigned)(unsigned short)f2bf(acc[ct][3]) << 16);
                uint2 v = {lo, hi};
                *reinterpret_cast<uint2*>(stash + (size_t)(base + lr) * COCH + ct * 16 + grp * 4) = v;
            }
        }
    }

    #pragma unroll
    for (int ct = 0; ct < 6; ++ct)
        #pragma unroll
        for (int r = 0; r < 4; ++r) {
            float s = sum[ct][r], q = sq[ct][r];
            s += __shfl_xor(s, 1);  q += __shfl_xor(q, 1);
            s += __shfl_xor(s, 2);  q += __shfl_xor(q, 2);
            s += __shfl_xor(s, 4);  q += __shfl_xor(q, 4);
            s += __shfl_xor(s, 8);  q += __shfl_xor(q, 8);
            if (lr == 0) {
                sredS[wv][ct * 16 + grp * 4 + r] = s;
                sredQ[wv][ct * 16 + grp * 4 + r] = q;
            }
        }
    __syncthreads();
    if (threadIdx.x < COCH) {
        int c = threadIdx.x;
        atomicAdd(&ws[GSUM_OFF + c], sredS[0][c] + sredS[1][c] + sredS[2][c] + sredS[3][c]);
        atomicAdd(&ws[GSQ_OFF + c],  sredQ[0][c] + sredQ[1][c] + sredQ[2][c] + sredQ[3][c]);
    }
}

// K2S: pure streaming pass 2 — read bf16 stash, scale+bias+ReLU, write f32 out.
// Reverse order harvests the L3-resident stash tail; NT stores for out.
__global__ __launch_bounds__(256, 8) void k2s(const float* __restrict__ gamma,
                                              const float* __restrict__ beta,
                                              const float* __restrict__ ws,
                                              float* __restrict__ out) {
    __shared__ __align__(16) float sScale[COCH];
    __shared__ __align__(16) float sBias[COCH];
    if (threadIdx.x < COCH) {
        int c = threadIdx.x;
        float mean = ws[GSUM_OFF + c] * (1.f / (float)N_PTS);
        float var  = ws[GSQ_OFF + c] * (1.f / (float)N_PTS) - mean * mean;
        float scl  = gamma[c] * rsqrtf(var + BN_EPS);
        sScale[c] = scl;
        sBias[c]  = beta[c] - mean * scl;
    }
    __syncthreads();

    const short8* stash8 = (const short8*)(ws + STASH_OFF_F);
    const long U = (long)N_PTS * COCH / 8;   // 18,000,000 units of 8 channels
    const long stride = (long)gridDim.x * blockDim.x;
    const long gtid = (long)blockIdx.x * blockDim.x + threadIdx.x;

    for (long u = U - 1 - gtid; u >= 0; u -= stride) {
        unsigned c12 = (unsigned)(u % 12u);          // channel-octet within point
        int cb = (int)c12 * 8;
        short8 s = stash8[u];
        f32x4 sc0 = *reinterpret_cast<const f32x4*>(&sScale[cb]);
        f32x4 sc1 = *reinterpret_cast<const f32x4*>(&sScale[cb + 4]);
        f32x4 bs0 = *reinterpret_cast<const f32x4*>(&sBias[cb]);
        f32x4 bs1 = *reinterpret_cast<const f32x4*>(&sBias[cb + 4]);
        f32x4 y0, y1;
        #pragma unroll
        for (int j = 0; j < 4; ++j) {
            float x0 = __uint_as_float(((unsigned)(unsigned short)s[j]) << 16);
            float x1 = __uint_as_float(((unsigned)(unsigned short)s[4 + j]) << 16);
            y0[j] = fmaxf(x0 * sc0[j] + bs0[j], 0.f);
            y1[j] = fmaxf(x1 * sc1[j] + bs1[j], 0.f);
        }
        f32x4* o = reinterpret_cast<f32x4*>(out + u * 8);
        __builtin_nontemporal_store(y0, o);
        __builtin_nontemporal_store(y1, o + 1);
    }
}

// K3 fallback (R3 verbatim): recompute GEMM, normalize, ReLU, NT store, reverse.
__global__ __launch_bounds__(256, 2) void k3_fb(const float* __restrict__ bb,
                                                const int* __restrict__ bidx,
                                                const float* __restrict__ W,
                                                const float* __restrict__ gamma,
                                                const float* __restrict__ beta,
                                                const float* __restrict__ ws,
                                                float* __restrict__ out) {
    __shared__ __align__(16) short sW[6 * 3 * 64 * 8];
    __shared__ __align__(16) float sT[NB * STPAD];
    __shared__ __align__(16) float sScale[COCH];
    __shared__ __align__(16) float sBias[COCH];

    stage_W(W, sW);
    for (int i = threadIdx.x; i < NB * COCH; i += blockDim.x)
        sT[(i / COCH) * STPAD + (i % COCH)] = ws[T_OFF + i];
    if (threadIdx.x < COCH) {
        int c = threadIdx.x;
        float mean = ws[GSUM_OFF + c] * (1.f / (float)N_PTS);
        float var  = ws[GSQ_OFF + c] * (1.f / (float)N_PTS) - mean * mean;
        float scl  = gamma[c] * rsqrtf(var + BN_EPS);
        sScale[c] = scl;
        sBias[c]  = beta[c] - mean * scl;
    }
    __syncthreads();

    const int lane = threadIdx.x & 63;
    const int wv = threadIdx.x >> 6;
    const int grp = lane >> 4, lr = lane & 15;

    bf16x8 bf[6][3];
    load_bfrag_lds(sW, lane, bf);

    f32x4 sc[6], bs[6];
    #pragma unroll
    for (int ct = 0; ct < 6; ++ct) {
        sc[ct] = *reinterpret_cast<const f32x4*>(&sScale[ct * 16 + grp * 4]);
        bs[ct] = *reinterpret_cast<const f32x4*>(&sBias[ct * 16 + grp * 4]);
    }

    const int gw = blockIdx.x * 4 + wv;
    for (int t = NT_TILES - 1 - gw; t >= 0; t -= NWAVE) {
        int base = t * 16;
        f32x4 acc[6];
        tile_acc<false>(bb, bidx, sT, bf, base, grp, lr, acc);
        #pragma unroll
        for (int ct = 0; ct < 6; ++ct) {
            f32x4 y;
            #pragma unroll
            for (int r = 0; r < 4; ++r)
                y[r] = fmaxf(acc[ct][r] * sc[ct][r] + bs[ct][r], 0.f);
            __builtin_nontemporal_store(y,
                reinterpret_cast<f32x4*>(out + (size_t)(base + lr) * COCH + ct * 16 + grp * 4));
        }
    }
}

extern "C" void kernel_launch(void* const* d_in, const int* in_sizes, int n_in,
                              void* d_out, int out_size, void* d_ws, size_t ws_size,
                              hipStream_t stream) {
    const float* bb    = (const float*)d_in[0];
    const int*   bidx  = (const int*)d_in[1];
    const float* text  = (const float*)d_in[2];
    const float* W     = (const float*)d_in[3];
    const float* gamma = (const float*)d_in[4];
    const float* beta  = (const float*)d_in[5];
    float* out = (float*)d_out;
    float* ws  = (float*)d_ws;

    const int do_stash = (ws_size >= WS_NEEDED) ? 1 : 0;

    hipLaunchKernelGGL(k0_init, dim3(NB + 1), dim3(128), 0, stream, text, W, ws);
    hipLaunchKernelGGL(k1_stats, dim3(GRID1), dim3(256), 0, stream, bb, bidx, W, ws, do_stash);
    if (do_stash) {
        hipLaunchKernelGGL(k2s, dim3(2048), dim3(256), 0, stream, gamma, beta, ws, out);
    } else {
        hipLaunchKernelGGL(k3_fb, dim3(GRID1), dim3(256), 0, stream, bb, bidx, W, gamma, beta, ws, out);
    }
}